// Round 2
// baseline (429.006 us; speedup 1.0000x reference)
//
#include <hip/hip_runtime.h>

// SpikeLoss: loss = 0.5 * sum((outputs - psp(target))^2)
// psp: syn_t = syn_{t-1}*decay + x_t ; psp_t = syn_t/tau, decay = 1 - 1/tau.
//
// R5b: identical design to R5 (round-1 bench was an infra failure, kernel
// never ran). Latency/duty-cycle attack on R4's 6-waves/CU + per-tile
// vmcnt(0) drain:
//  - stage ONLY target via global_load_lds; outputs read direct (coalesced f4),
//    paired with psp through an in-place LDS round trip.
//  - 64-thread (1-wave) blocks, PIX=16: LDS = 2 x 6.4 KB -> 12 blocks/CU
//    (12 waves/CU), ZERO barriers (single wave; lgkmcnt fences only).
//  - counted s_waitcnt vmcnt(7): next tile's 7 DMA loads stay in flight
//    across the wait for the current tile — queue never drains mid-loop.
//  - process: thread (p = tid>>2, q = tid&3) scans a 25-elem segment with
//    zero carry-in; true carry combined via __shfl_up with decay^{25k}
//    weights (tau=2 -> 2^-25, exact in effect); true syn written back
//    in place. pass2: d = fmaf(syn, -1/tau, out); acc += d*d.

constexpr int T   = 100;   // trailing axis length
constexpr int SEG = 25;    // elements per thread-segment
constexpr int PIX = 16;    // pixels per tile
constexpr int TF  = PIX * T;            // 1600 floats = 6.4 KB per tile
constexpr int NCH = (TF * 4) / 1024;    // 6 full 1-KB DMA chunks (1536 floats)
constexpr int NV4 = TF / 4;             // 400 float4 per tile

typedef const __attribute__((address_space(1))) void* gas_t;
typedef __attribute__((address_space(3))) void*       las_t;
typedef float f4 __attribute__((ext_vector_type(4)));

__global__ __launch_bounds__(64) void spike_loss_kernel(
    const float* __restrict__ tgt,
    const float* __restrict__ outs,
    const int*   __restrict__ tau_p,
    float*       __restrict__ out,     // [1], pre-zeroed
    int n_tiles, int tiles_per_block)
{
    __shared__ __align__(16) float lds_t[2][TF];

    const float tau     = (float)tau_p[0];
    const float inv_tau = 1.0f / tau;
    const float decay   = 1.0f - inv_tau;
    float d25 = 1.0f;
    #pragma unroll
    for (int i = 0; i < SEG; ++i) d25 *= decay;   // decay^25
    const float d50 = d25 * d25;

    const int tid = threadIdx.x;                  // 0..63, one wave

    const int first = blockIdx.x * tiles_per_block;
    int cnt = n_tiles - first;
    if (cnt < 0) cnt = 0;
    if (cnt > tiles_per_block) cnt = tiles_per_block;
    if (cnt <= 0) return;                         // single wave: safe

    float acc = 0.0f;

    // ---- DMA stage: exactly 7 loads (6 x w16 + 1 x w4) for the target tile
    auto stage = [&](int tile, int buf) {
        const float* gt = tgt + (size_t)tile * TF;
        #pragma unroll
        for (int c = 0; c < NCH; ++c) {
            __builtin_amdgcn_global_load_lds((gas_t)(gt + c * 256 + tid * 4),
                (las_t)&lds_t[buf][c * 256], 16, 0, 0);
        }
        // 256-B tail: floats [1536, 1600)
        __builtin_amdgcn_global_load_lds((gas_t)(gt + NCH * 256 + tid),
            (las_t)&lds_t[buf][NCH * 256], 4, 0, 0);
    };

    // ---- scan: compute true syn for this tile, write back in place
    auto process = [&](int buf) {
        const int p    = tid >> 2;            // pixel in tile, 0..15
        const int q    = tid & 3;             // segment in pixel
        const int base = p * T + q * SEG;

        float s[SEG];
        float syn = 0.0f;
        #pragma unroll
        for (int i = 0; i < SEG; ++i) {
            syn = fmaf(syn, decay, lds_t[buf][base + i]);
            s[i] = syn;
        }
        // carry into segment q = true syn at end of segment q-1:
        // S_{q-1} = E_{q-1} + d25*E_{q-2} + d50*E_{q-3}
        const float f1 = __shfl_up(syn, 1, 64);
        const float f2 = __shfl_up(syn, 2, 64);
        const float f3 = __shfl_up(syn, 3, 64);
        float carry = (q >= 1) ? f1 : 0.0f;
        if (q >= 2) carry = fmaf(f2, d25, carry);
        if (q >= 3) carry = fmaf(f3, d50, carry);

        float cp = carry;
        #pragma unroll
        for (int i = 0; i < SEG; ++i) {
            cp *= decay;                           // carry*decay^{i+1}
            lds_t[buf][base + i] = s[i] + cp;      // true syn, in place
        }
    };

    // ---- pass2: lane-contiguous f4 over the tile; outs direct from global
    auto pass2 = [&](int tile, int buf) {
        const f4* o4 = (const f4*)(outs + (size_t)tile * TF);
        const f4* p4 = (const f4*)lds_t[buf];
        #pragma unroll
        for (int j = 0; j < NV4 / 64; ++j) {       // 6 full rounds
            const int idx = tid + 64 * j;
            const f4 o = o4[idx];
            const f4 sy = p4[idx];
            #pragma unroll
            for (int c = 0; c < 4; ++c) {
                const float d = fmaf(sy[c], -inv_tau, o[c]);
                acc = fmaf(d, d, acc);
            }
        }
        if (tid < NV4 - (NV4 / 64) * 64) {         // 16-thread tail
            const int idx = (NV4 / 64) * 64 + tid;
            const f4 o = o4[idx];
            const f4 sy = p4[idx];
            #pragma unroll
            for (int c = 0; c < 4; ++c) {
                const float d = fmaf(sy[c], -inv_tau, o[c]);
                acc = fmaf(d, d, acc);
            }
        }
    };

    stage(first, 0);

    for (int k = 0; k < cnt; ++k) {
        if (k + 1 < cnt) {
            stage(first + k + 1, (k + 1) & 1);     // prefetch stays in flight
            asm volatile("s_waitcnt vmcnt(7)" ::: "memory");  // tile k landed
        } else {
            asm volatile("s_waitcnt vmcnt(0)" ::: "memory");
        }
        process(k & 1);
        // syn writes visible before pass2's ds_reads (same wave; ordering fence)
        asm volatile("s_waitcnt lgkmcnt(0)" ::: "memory");
        pass2(first + k, k & 1);
        // pass2's ds_reads retired before next stage can overwrite this buffer
        asm volatile("s_waitcnt lgkmcnt(0)" ::: "memory");
    }

    // ---- reduction: single wave -> shuffle + one atomic
    #pragma unroll
    for (int off = 32; off > 0; off >>= 1)
        acc += __shfl_down(acc, off, 64);
    if (tid == 0)
        atomicAdd(out, 0.5f * acc);
}

extern "C" void kernel_launch(void* const* d_in, const int* in_sizes, int n_in,
                              void* d_out, int out_size, void* d_ws, size_t ws_size,
                              hipStream_t stream) {
    const float* outs = (const float*)d_in[0];   // outputs [B,C,H,W,T]
    const float* tgt  = (const float*)d_in[1];   // target  [B,C,H,W,T]
    const int* tau_p  = (const int*)d_in[3];     // tau_s
    float* out        = (float*)d_out;

    const int n_pixels = in_sizes[0] / T;        // 524288
    const int n_tiles  = n_pixels / PIX;         // 32768

    const int block = 64;                        // 1 wave
    const int grid  = 3072;                      // 12 blocks/CU (LDS: 12.8 KB)
    const int tiles_per_block = (n_tiles + grid - 1) / grid;  // 11

    // d_out is poisoned to 0xAA before every call — zero it (graph-capturable).
    hipMemsetAsync(out, 0, sizeof(float), stream);

    spike_loss_kernel<<<grid, block, 0, stream>>>(
        tgt, outs, tau_p, out, n_tiles, tiles_per_block);
}

// Round 3
// 419.213 us; speedup vs baseline: 1.0234x; 1.0234x over previous
//
#include <hip/hip_runtime.h>

// SpikeLoss: loss = 0.5 * sum((outputs - psp(target))^2)
// psp: syn_t = syn_{t-1}*decay + x_t ; psp_t = syn_t/tau, decay = 1 - 1/tau.
//
// R6: fix R5's self-defeating pipeline. vmcnt retires IN ISSUE ORDER, so
// R5's pass2 direct global loads (issued after the prefetch DMAs) forced the
// whole prefetch to retire every tile — burst-and-drain, same as R4.
//  - consume path has ZERO VMEM ops: both arrays staged to LDS by DMA,
//    fused scan+diff reads only LDS (R4-style consume, R5-style tiles).
//  - counted s_waitcnt vmcnt(14): tile k+1's 14 DMA loads stay in flight
//    across the entire consume of tile k. Queue never drains mid-loop.
//  - 64-thread (1-wave) blocks, PIX=16: LDS = 2 bufs x 2 arrays x 6.4 KB
//    = 25.6 KB -> 6 blocks/CU, zero barriers.
//  - consume via ds_read_b128: thread (p=tid>>2, q=tid&3) owns a 28-float
//    segment at byte offset p*400 + q*112 (16B-aligned; bank-start pattern
//    (4p+28q) mod 32 hits the b128 floor, conflict-free). q==3 covers the
//    16-float tail. Carry via __shfl_up with decay^{28,56} weights
//    (tau=2 -> 2^-28: below fp32 eps relative, exact in effect).

constexpr int T   = 100;   // trailing axis length
constexpr int PIX = 16;    // pixels per tile
constexpr int TF  = PIX * T;            // 1600 floats = 6.4 KB per array
constexpr int NCH = (TF * 4) / 1024;    // 6 full 1-KB DMA chunks (1536 floats)

typedef const __attribute__((address_space(1))) void* gas_t;
typedef __attribute__((address_space(3))) void*       las_t;
typedef float f4 __attribute__((ext_vector_type(4)));

__global__ __launch_bounds__(64) void spike_loss_kernel(
    const float* __restrict__ tgt,
    const float* __restrict__ outs,
    const int*   __restrict__ tau_p,
    float*       __restrict__ out,     // [1], pre-zeroed
    int n_tiles, int tiles_per_block)
{
    __shared__ __align__(16) float lds_t[2][TF];
    __shared__ __align__(16) float lds_o[2][TF];

    const float tau     = (float)tau_p[0];
    const float inv_tau = 1.0f / tau;
    const float decay   = 1.0f - inv_tau;
    float d28 = 1.0f;
    #pragma unroll
    for (int i = 0; i < 28; ++i) d28 *= decay;    // decay^28
    const float d56 = d28 * d28;

    const int tid = threadIdx.x;                  // 0..63, one wave

    const int first = blockIdx.x * tiles_per_block;
    int cnt = n_tiles - first;
    if (cnt < 0) cnt = 0;
    if (cnt > tiles_per_block) cnt = tiles_per_block;
    if (cnt <= 0) return;                         // single wave: safe

    float acc = 0.0f;

    // ---- DMA stage: 14 loads per tile (per array: 6 x w16 + 1 x w4) ----
    auto stage = [&](int tile, int buf) {
        const float* gt = tgt  + (size_t)tile * TF;
        const float* go = outs + (size_t)tile * TF;
        #pragma unroll
        for (int c = 0; c < NCH; ++c) {
            __builtin_amdgcn_global_load_lds((gas_t)(gt + c * 256 + tid * 4),
                (las_t)&lds_t[buf][c * 256], 16, 0, 0);
            __builtin_amdgcn_global_load_lds((gas_t)(go + c * 256 + tid * 4),
                (las_t)&lds_o[buf][c * 256], 16, 0, 0);
        }
        // 256-B tails: floats [1536, 1600)
        __builtin_amdgcn_global_load_lds((gas_t)(gt + NCH * 256 + tid),
            (las_t)&lds_t[buf][NCH * 256], 4, 0, 0);
        __builtin_amdgcn_global_load_lds((gas_t)(go + NCH * 256 + tid),
            (las_t)&lds_o[buf][NCH * 256], 4, 0, 0);
    };

    // ---- fused consume: scan + diff + accumulate, LDS-only ----
    auto consume = [&](int buf) {
        const int p  = tid >> 2;              // pixel in tile, 0..15
        const int q  = tid & 3;               // segment in pixel
        const int fb = p * T + q * 28;        // float index of segment start
        const f4* tb = (const f4*)&lds_t[buf][fb];
        const f4* ob = (const f4*)&lds_o[buf][fb];
        const int segn = (q == 3) ? 16 : 28;  // q==3: elements 84..99

        // zero-carry scan of own segment (b128 reads, conflict-free)
        float s[28];
        float syn = 0.0f;
        #pragma unroll
        for (int j = 0; j < 7; ++j) {
            if (j * 4 < segn) {
                const f4 v = tb[j];
                #pragma unroll
                for (int c = 0; c < 4; ++c) {
                    syn = fmaf(syn, decay, v[c]);
                    s[j * 4 + c] = syn;
                }
            }
        }
        // carry into segment q = true syn at end of segment q-1:
        // S_{q-1} = E_{q-1} + d28*E_{q-2} + d56*E_{q-3}
        const float f1 = __shfl_up(syn, 1, 64);
        const float f2 = __shfl_up(syn, 2, 64);
        const float f3 = __shfl_up(syn, 3, 64);
        float carry = (q >= 1) ? f1 : 0.0f;
        if (q >= 2) carry = fmaf(f2, d28, carry);
        if (q >= 3) carry = fmaf(f3, d56, carry);

        float cp = carry;
        #pragma unroll
        for (int j = 0; j < 7; ++j) {
            if (j * 4 < segn) {
                const f4 ov = ob[j];
                #pragma unroll
                for (int c = 0; c < 4; ++c) {
                    cp *= decay;                          // carry*decay^{i+1}
                    const float st = s[j * 4 + c] + cp;   // true syn
                    const float d  = fmaf(st, -inv_tau, ov[c]);
                    acc = fmaf(d, d, acc);
                }
            }
        }
    };

    stage(first, 0);

    for (int k = 0; k < cnt; ++k) {
        const int buf = k & 1;
        if (k + 1 < cnt) {
            stage(first + k + 1, buf ^ 1);   // 14 loads, stay in flight
            // tile k's 14 retired; tile k+1's 14 remain outstanding
            asm volatile("s_waitcnt vmcnt(14)" ::: "memory");
        } else {
            asm volatile("s_waitcnt vmcnt(0)" ::: "memory");
        }
        consume(buf);
        // consume's ds_reads retired before tile k+2's DMA can touch this buf
        asm volatile("s_waitcnt lgkmcnt(0)" ::: "memory");
    }

    // ---- reduction: single wave -> shuffle + one atomic ----
    #pragma unroll
    for (int off = 32; off > 0; off >>= 1)
        acc += __shfl_down(acc, off, 64);
    if (tid == 0)
        atomicAdd(out, 0.5f * acc);
}

extern "C" void kernel_launch(void* const* d_in, const int* in_sizes, int n_in,
                              void* d_out, int out_size, void* d_ws, size_t ws_size,
                              hipStream_t stream) {
    const float* outs = (const float*)d_in[0];   // outputs [B,C,H,W,T]
    const float* tgt  = (const float*)d_in[1];   // target  [B,C,H,W,T]
    const int* tau_p  = (const int*)d_in[3];     // tau_s
    float* out        = (float*)d_out;

    const int n_pixels = in_sizes[0] / T;        // 524288
    const int n_tiles  = n_pixels / PIX;         // 32768

    const int block = 64;                        // 1 wave
    const int grid  = 1536;                      // 6 blocks/CU (LDS: 25.6 KB)
    const int tiles_per_block = (n_tiles + grid - 1) / grid;  // 22

    // d_out is poisoned to 0xAA before every call — zero it (graph-capturable).
    hipMemsetAsync(out, 0, sizeof(float), stream);

    spike_loss_kernel<<<grid, block, 0, stream>>>(
        tgt, outs, tau_p, out, n_tiles, tiles_per_block);
}